// Round 2
// baseline (262.184 us; speedup 1.0000x reference)
//
#include <hip/hip_runtime.h>
#include <stdint.h>

typedef unsigned int   u32;
typedef unsigned long long u64;

#define Bb   128
#define Nn   4096
#define DW   64
#define TPB  256
#define PERT (Nn / TPB)   // 16 consecutive elements per thread
#define NBINS 4096
#define LCAP 512
#define CCAP 1024
#define BPR  8

// One block per row: select n_neg smallest-priority absent slots (stable by
// (prio, index)), then stable compaction of (present | negative) slot indices.
// If DO_COPY, also performs the gather (fallback when ws too small).
template<bool DO_COPY>
__global__ __launch_bounds__(TPB) void sel_kernel(
    const float* __restrict__ zwhere, const float* __restrict__ zpres,
    const float* __restrict__ zwhat,  const float* __restrict__ zdepth,
    const float* __restrict__ nprio,
    float* __restrict__ out0, float* __restrict__ out1,
    float* __restrict__ out2, float* __restrict__ out3,
    int* __restrict__ srcws, int K)
{
    __shared__ float prio[Nn];      // 16 KB
    __shared__ u32   hist[NBINS];   // 16 KB
    __shared__ u64   blist[LCAP];   //  4 KB
    __shared__ int   compact[CCAP]; //  4 KB
    __shared__ u64   presb[Nn / 64];//  512 B present bitmask
    __shared__ int   cnt[TPB];      //  1 KB
    __shared__ int   s_np, s_m, s_bstar, s_cbefore;
    __shared__ u64   s_thr;

    const int b   = blockIdx.x;
    const int tid = threadIdx.x;

    for (int i = tid; i < NBINS; i += TPB) hist[i] = 0;
    for (int i = tid; i < Nn / 64; i += TPB) presb[i] = 0;
    if (tid == 0) { s_np = 0; s_m = 0; s_bstar = -1; s_cbefore = 0; s_thr = 0; }
    __syncthreads();

    // load priorities, build present bitmask, count present, histogram absent
    int myp = 0;
    for (int i = tid; i < Nn; i += TPB) {
        float z = zpres[(size_t)b * Nn + i];
        float p = nprio[(size_t)b * Nn + i];
        prio[i] = p;
        if (z != 0.0f) {
            myp++;
            atomicOr(&presb[i >> 6], 1ull << (i & 63));
        } else {
            int bin = (int)(p * (float)NBINS);
            bin = bin < 0 ? 0 : (bin > NBINS - 1 ? NBINS - 1 : bin);
            atomicAdd(&hist[bin], 1u);
        }
    }
    atomicAdd(&s_np, myp);
    __syncthreads();

    const int n_neg = K - s_np;

    // block scan over per-thread bin-range sums to locate the boundary bin
    int hl = 0;
    #pragma unroll
    for (int j = 0; j < NBINS / TPB; j++) hl += (int)hist[tid * (NBINS / TPB) + j];
    cnt[tid] = hl;
    __syncthreads();
    for (int d = 1; d < TPB; d <<= 1) {
        int v = (tid >= d) ? cnt[tid - d] : 0;
        __syncthreads();
        cnt[tid] += v;
        __syncthreads();
    }
    {
        int hincl = cnt[tid];
        int hbase = hincl - hl;
        if (n_neg > hbase && n_neg <= hincl) {
            int c = hbase;
            for (int j = 0; j < NBINS / TPB; j++) {
                int h = (int)hist[tid * (NBINS / TPB) + j];
                if (n_neg <= c + h) { s_bstar = tid * (NBINS / TPB) + j; s_cbefore = c; break; }
                c += h;
            }
        }
    }
    __syncthreads();
    const int bstar = s_bstar;
    const int r     = n_neg - s_cbefore;   // 1..hist[bstar]

    // collect boundary-bin keys; exact r-th smallest by (prio_bits, index)
    for (int i = tid; i < Nn; i += TPB) {
        if (!((presb[i >> 6] >> (i & 63)) & 1ull)) {
            int bin = (int)(prio[i] * (float)NBINS);
            bin = bin < 0 ? 0 : (bin > NBINS - 1 ? NBINS - 1 : bin);
            if (bin == bstar) {
                int pos = atomicAdd(&s_m, 1);
                if (pos < LCAP)
                    blist[pos] = (((u64)__float_as_uint(prio[i])) << 12) | (u64)i;
            }
        }
    }
    __syncthreads();
    int m = s_m; if (m > LCAP) m = LCAP;
    for (int j = tid; j < m; j += TPB) {
        u64 kj = blist[j];
        int rank = 0;
        for (int l = 0; l < m; l++) rank += (blist[l] < kj) ? 1 : 0;
        if (rank == r - 1) s_thr = kj;   // keys unique (index in low bits)
    }
    __syncthreads();
    const u64 thr = s_thr;

    // selection flags over 16 consecutive elems/thread + stable compaction
    int lc = 0;
    u32 selbits = 0, negbits = 0;
    const int base_n = tid * PERT;
    #pragma unroll
    for (int j = 0; j < PERT; j++) {
        int n = base_n + j;
        bool present = (presb[n >> 6] >> (n & 63)) & 1ull;
        bool neg = false;
        if (!present) {
            int bin = (int)(prio[n] * (float)NBINS);
            bin = bin < 0 ? 0 : (bin > NBINS - 1 ? NBINS - 1 : bin);
            u64 key = (((u64)__float_as_uint(prio[n])) << 12) | (u64)n;
            neg = (bin < bstar) || (bin == bstar && key <= thr);
        }
        if (present || neg) { selbits |= (1u << j); lc++; }
        if (neg) negbits |= (1u << j);
    }
    cnt[tid] = lc;
    __syncthreads();
    for (int d = 1; d < TPB; d <<= 1) {
        int v = (tid >= d) ? cnt[tid - d] : 0;
        __syncthreads();
        cnt[tid] += v;
        __syncthreads();
    }
    int pos = cnt[tid] - lc;
    #pragma unroll
    for (int j = 0; j < PERT; j++) {
        if (selbits & (1u << j)) {
            int n = base_n + j;
            bool neg = (negbits >> j) & 1;
            if (pos < CCAP && pos < K) {
                compact[pos] = n | (neg ? (1 << 30) : 0);
                out1[(size_t)b * K + pos] = neg ? -1.0f : 1.0f; // z_present in {0,1}
            }
            pos++;
        }
    }
    __syncthreads();

    if (!DO_COPY) {
        for (int k = tid; k < K; k += TPB)
            srcws[(size_t)b * K + k] = compact[k];
        return;
    }

    // fused gather fallback
    for (int i = tid; i < K * 16; i += TPB) {
        int k = i >> 4, lane = i & 15;
        int e = compact[k];
        int src = e & (Nn - 1);
        bool neg = (e >> 30) & 1;
        float4 v = make_float4(0.f, 0.f, 0.f, 0.f);
        if (!neg) v = *(const float4*)(zwhat + ((size_t)(b * Nn + src) * DW + lane * 4));
        *(float4*)(out2 + ((size_t)(b * K + k) * DW + lane * 4)) = v;
    }
    for (int k = tid; k < K; k += TPB) {
        int e = compact[k];
        int src = e & (Nn - 1);
        bool neg = (e >> 30) & 1;
        float4 w = *(const float4*)(zwhere + (size_t)(b * Nn + src) * 4);
        float mv = (w.z >= w.w) ? w.z : w.w;   // argmax ties -> first
        float4 o; o.x = w.x; o.y = w.y; o.z = mv; o.w = mv;
        *(float4*)(out0 + (size_t)(b * K + k) * 4) = o;
        out3[(size_t)b * K + k] = neg ? 0.0f : zdepth[(size_t)b * Nn + src];
    }
}

// Pure gather: BPR blocks per row for machine-wide occupancy.
__global__ __launch_bounds__(TPB) void copy_kernel(
    const float* __restrict__ zwhere, const float* __restrict__ zwhat,
    const float* __restrict__ zdepth, const int* __restrict__ srcws,
    float* __restrict__ out0, float* __restrict__ out2, float* __restrict__ out3,
    int K, int spb)
{
    int b = blockIdx.x / BPR;
    int chunk = blockIdx.x % BPR;
    int k0 = chunk * spb;
    int k1 = k0 + spb; if (k1 > K) k1 = K;
    int tid = threadIdx.x;

    // z_what_loc: 16 lanes x 16B per slot (256 B contiguous per slot)
    for (int i = k0 * 16 + tid; i < k1 * 16; i += TPB) {
        int k = i >> 4, lane = i & 15;
        int e = srcws[(size_t)b * K + k];
        int src = e & (Nn - 1);
        bool neg = (e >> 30) & 1;
        float4 v = make_float4(0.f, 0.f, 0.f, 0.f);
        if (!neg) v = *(const float4*)(zwhat + ((size_t)(b * Nn + src) * DW + lane * 4));
        *(float4*)(out2 + ((size_t)(b * K + k) * DW + lane * 4)) = v;
    }
    // z_where_sq (16 B) + depth (4 B): one lane per slot
    for (int k = k0 + tid; k < k1; k += TPB) {
        int e = srcws[(size_t)b * K + k];
        int src = e & (Nn - 1);
        bool neg = (e >> 30) & 1;
        float4 w = *(const float4*)(zwhere + (size_t)(b * Nn + src) * 4);
        float mv = (w.z >= w.w) ? w.z : w.w;   // argmax ties -> first
        float4 o; o.x = w.x; o.y = w.y; o.z = mv; o.w = mv;
        *(float4*)(out0 + (size_t)(b * K + k) * 4) = o;
        out3[(size_t)b * K + k] = neg ? 0.0f : zdepth[(size_t)b * Nn + src];
    }
}

extern "C" void kernel_launch(void* const* d_in, const int* in_sizes, int n_in,
                              void* d_out, int out_size, void* d_ws, size_t ws_size,
                              hipStream_t stream) {
    const float* zwhere = (const float*)d_in[0];
    const float* zpres  = (const float*)d_in[1];
    const float* zwhat  = (const float*)d_in[2];
    // d_in[3] z_what_scale, d_in[5] z_depth_scale: dead (only *_loc reach outputs)
    const float* zdepth = (const float*)d_in[4];
    const float* nprio  = (const float*)d_in[6];
    // d_in[7] n_objects: recover K host-side from out_size = B*K*(4+1+64+1)
    int K = out_size / (Bb * 70);

    float* out  = (float*)d_out;
    float* out0 = out;
    float* out1 = out0 + (size_t)Bb * K * 4;
    float* out2 = out1 + (size_t)Bb * K;
    float* out3 = out2 + (size_t)Bb * K * DW;

    size_t need = (size_t)Bb * K * sizeof(int);
    if (ws_size >= need) {
        int* srcws = (int*)d_ws;
        sel_kernel<false><<<Bb, TPB, 0, stream>>>(zwhere, zpres, zwhat, zdepth, nprio,
                                                  out0, out1, out2, out3, srcws, K);
        int spb = (K + BPR - 1) / BPR;
        copy_kernel<<<Bb * BPR, TPB, 0, stream>>>(zwhere, zwhat, zdepth, srcws,
                                                  out0, out2, out3, K, spb);
    } else {
        sel_kernel<true><<<Bb, TPB, 0, stream>>>(zwhere, zpres, zwhat, zdepth, nprio,
                                                 out0, out1, out2, out3, nullptr, K);
    }
}

// Round 3
// 253.236 us; speedup vs baseline: 1.0353x; 1.0353x over previous
//
#include <hip/hip_runtime.h>
#include <stdint.h>

typedef unsigned int   u32;
typedef unsigned long long u64;

#define Bb   128
#define Nn   4096
#define DW   64
#define TPB  256
#define PERT 16          // contiguous slots per thread (Nn / TPB)
#define NBINS 4096
#define LCAP 512
#define CCAP 1024
#define BPR  8

// inclusive scan across the 64-lane wave
__device__ __forceinline__ int wave_iscan(int v) {
    int lane = threadIdx.x & 63;
    #pragma unroll
    for (int d = 1; d < 64; d <<= 1) {
        int u = __shfl_up(v, d, 64);
        v += (lane >= d) ? u : 0;
    }
    return v;
}

// block-wide exclusive scan over TPB threads (4 waves); 1 barrier.
// wsum must be a distinct int[4] per call site (no reuse hazard).
__device__ __forceinline__ int block_escan(int v, int* wsum) {
    int tid  = threadIdx.x;
    int wid  = tid >> 6;
    int incl = wave_iscan(v);
    if ((tid & 63) == 63) wsum[wid] = incl;
    __syncthreads();
    int base = 0;
    #pragma unroll
    for (int w = 0; w < TPB / 64; w++) base += (w < wid) ? wsum[w] : 0;
    return base + incl - v;
}

// One block per row. Select n_neg smallest-priority absent slots (stable by
// (prio, index)), then stable compaction of (present | negative) slot indices
// into srcws (bit30 = negative). If DO_COPY, also gathers outputs (fallback).
template<bool DO_COPY>
__global__ __launch_bounds__(TPB) void sel_kernel(
    const float* __restrict__ zwhere, const float* __restrict__ zpres,
    const float* __restrict__ zwhat,  const float* __restrict__ zdepth,
    const float* __restrict__ nprio,
    float* __restrict__ out0, float* __restrict__ out1,
    float* __restrict__ out2, float* __restrict__ out3,
    int* __restrict__ srcws, int K)
{
    __shared__ u32 hist[NBINS];     // 16 KB
    __shared__ u64 blist[LCAP];     //  4 KB
    __shared__ int compact[CCAP];   //  4 KB
    __shared__ int wsumA[4], wsumB[4];
    __shared__ int s_m, s_bstar, s_cbefore, s_np;
    __shared__ u64 s_thr;

    const int b   = blockIdx.x;
    const int tid = threadIdx.x;

    for (int i = tid; i < NBINS; i += TPB) hist[i] = 0;
    if (tid == 0) { s_m = 0; s_bstar = -1; s_cbefore = 0; s_np = 0; s_thr = 0; }

    // ---- register-resident load of 16 contiguous slots (4 x float4 each) ----
    float p[PERT];
    u32 pm = 0;   // present mask, bit j = slot tid*16+j present
    {
        const float4* zp4 = (const float4*)(zpres + (size_t)b * Nn);
        const float4* pr4 = (const float4*)(nprio + (size_t)b * Nn);
        #pragma unroll
        for (int q = 0; q < 4; q++) {
            float4 z  = zp4[tid * 4 + q];
            float4 pp = pr4[tid * 4 + q];
            p[4*q+0] = pp.x; p[4*q+1] = pp.y; p[4*q+2] = pp.z; p[4*q+3] = pp.w;
            if (z.x != 0.0f) pm |= 1u << (4*q+0);
            if (z.y != 0.0f) pm |= 1u << (4*q+1);
            if (z.z != 0.0f) pm |= 1u << (4*q+2);
            if (z.w != 0.0f) pm |= 1u << (4*q+3);
        }
    }
    __syncthreads();   // hist + s_* init complete

    // ---- histogram of absent-slot priorities (value bins, monotone) ----
    #pragma unroll
    for (int j = 0; j < PERT; j++) {
        if (!((pm >> j) & 1u)) {
            int bin = (int)(p[j] * (float)NBINS);
            bin = bin < 0 ? 0 : (bin > NBINS - 1 ? NBINS - 1 : bin);
            atomicAdd(&hist[bin], 1u);
        }
    }
    // present count: wave reduce + one atomic per wave
    {
        int myp = __popc(pm);
        #pragma unroll
        for (int d = 32; d >= 1; d >>= 1) myp += __shfl_down(myp, d, 64);
        if ((tid & 63) == 0) atomicAdd(&s_np, myp);
    }
    __syncthreads();

    const int n_neg = K - s_np;

    // ---- locate boundary bin: thread t owns bins [t*16, t*16+16) ----
    int hl = 0;
    #pragma unroll
    for (int j = 0; j < 16; j++) hl += (int)hist[tid * 16 + j];
    int hbase = block_escan(hl, wsumA);
    if (n_neg > hbase && n_neg <= hbase + hl) {
        int c = hbase;
        for (int j = 0; j < 16; j++) {
            int h = (int)hist[tid * 16 + j];
            if (n_neg <= c + h) { s_bstar = tid * 16 + j; s_cbefore = c; break; }
            c += h;
        }
    }
    __syncthreads();
    const int bstar = s_bstar;
    const int r     = n_neg - s_cbefore;   // 1..hist[bstar]

    // ---- boundary-bin candidates; exact r-th smallest by (prio_bits, idx) ----
    #pragma unroll
    for (int j = 0; j < PERT; j++) {
        if (!((pm >> j) & 1u)) {
            int bin = (int)(p[j] * (float)NBINS);
            bin = bin < 0 ? 0 : (bin > NBINS - 1 ? NBINS - 1 : bin);
            if (bin == bstar) {
                int pos = atomicAdd(&s_m, 1);
                if (pos < LCAP)
                    blist[pos] = (((u64)__float_as_uint(p[j])) << 12) | (u64)(tid * PERT + j);
            }
        }
    }
    __syncthreads();
    {
        int m = s_m; if (m > LCAP) m = LCAP;
        for (int j2 = tid; j2 < m; j2 += TPB) {
            u64 kj = blist[j2];
            int rank = 0;
            for (int l = 0; l < m; l++) rank += (blist[l] < kj) ? 1 : 0;
            if (rank == r - 1) s_thr = kj;   // keys unique (index in low bits)
        }
    }
    __syncthreads();
    const u64 thr = s_thr;

    // ---- selection bits + stable compaction (index order == (tid, j) order) ----
    u32 selbits = 0, negbits = 0;
    int lc = 0;
    #pragma unroll
    for (int j = 0; j < PERT; j++) {
        bool present = (pm >> j) & 1u;
        bool neg = false;
        if (!present) {
            int bin = (int)(p[j] * (float)NBINS);
            bin = bin < 0 ? 0 : (bin > NBINS - 1 ? NBINS - 1 : bin);
            u64 key = (((u64)__float_as_uint(p[j])) << 12) | (u64)(tid * PERT + j);
            neg = (bin < bstar) || (bin == bstar && key <= thr);
        }
        if (present || neg) { selbits |= 1u << j; lc++; }
        if (neg) negbits |= 1u << j;
    }
    int pos = block_escan(lc, wsumB);
    #pragma unroll
    for (int j = 0; j < PERT; j++) {
        if ((selbits >> j) & 1u) {
            if (pos < CCAP)
                compact[pos] = (tid * PERT + j) | ((((negbits >> j) & 1u)) << 30);
            pos++;
        }
    }
    __syncthreads();

    if (!DO_COPY) {
        for (int k = tid; k < K; k += TPB)
            srcws[(size_t)b * K + k] = compact[k];
        return;
    }

    // ---- fused gather fallback (ws too small) ----
    for (int i = tid; i < K * 16; i += TPB) {
        int k = i >> 4, lane = i & 15;
        int e = compact[k];
        int src = e & (Nn - 1);
        bool neg = (e >> 30) & 1;
        float4 v = make_float4(0.f, 0.f, 0.f, 0.f);
        if (!neg) v = *(const float4*)(zwhat + ((size_t)(b * Nn + src) * DW + lane * 4));
        *(float4*)(out2 + ((size_t)(b * K + k) * DW + lane * 4)) = v;
    }
    for (int k = tid; k < K; k += TPB) {
        int e = compact[k];
        int src = e & (Nn - 1);
        bool neg = (e >> 30) & 1;
        float4 w = *(const float4*)(zwhere + (size_t)(b * Nn + src) * 4);
        float mv = (w.z >= w.w) ? w.z : w.w;   // argmax ties -> first
        float4 o; o.x = w.x; o.y = w.y; o.z = mv; o.w = mv;
        *(float4*)(out0 + (size_t)(b * K + k) * 4) = o;
        out1[(size_t)b * K + k] = neg ? -1.0f : 1.0f;
        out3[(size_t)b * K + k] = neg ? 0.0f : zdepth[(size_t)b * Nn + src];
    }
}

// Pure gather: BPR blocks per row for machine-wide occupancy.
__global__ __launch_bounds__(TPB) void copy_kernel(
    const float* __restrict__ zwhere, const float* __restrict__ zwhat,
    const float* __restrict__ zdepth, const int* __restrict__ srcws,
    float* __restrict__ out0, float* __restrict__ out1,
    float* __restrict__ out2, float* __restrict__ out3,
    int K, int spb)
{
    int b     = blockIdx.x / BPR;
    int chunk = blockIdx.x % BPR;
    int k0 = chunk * spb;
    int k1 = k0 + spb; if (k1 > K) k1 = K;
    int tid = threadIdx.x;

    // z_what_loc: 16 lanes x 16 B per slot (256 B contiguous per slot)
    for (int i = k0 * 16 + tid; i < k1 * 16; i += TPB) {
        int k = i >> 4, lane = i & 15;
        int e = srcws[(size_t)b * K + k];
        int src = e & (Nn - 1);
        bool neg = (e >> 30) & 1;
        float4 v = make_float4(0.f, 0.f, 0.f, 0.f);
        if (!neg) v = *(const float4*)(zwhat + ((size_t)(b * Nn + src) * DW + lane * 4));
        *(float4*)(out2 + ((size_t)(b * K + k) * DW + lane * 4)) = v;
    }
    // z_where_sq (16 B) + modified (4 B) + depth (4 B): one lane per slot
    for (int k = k0 + tid; k < k1; k += TPB) {
        int e = srcws[(size_t)b * K + k];
        int src = e & (Nn - 1);
        bool neg = (e >> 30) & 1;
        float4 w = *(const float4*)(zwhere + (size_t)(b * Nn + src) * 4);
        float mv = (w.z >= w.w) ? w.z : w.w;   // argmax ties -> first
        float4 o; o.x = w.x; o.y = w.y; o.z = mv; o.w = mv;
        *(float4*)(out0 + (size_t)(b * K + k) * 4) = o;
        out1[(size_t)b * K + k] = neg ? -1.0f : 1.0f;   // z_present in {0,1}
        out3[(size_t)b * K + k] = neg ? 0.0f : zdepth[(size_t)b * Nn + src];
    }
}

extern "C" void kernel_launch(void* const* d_in, const int* in_sizes, int n_in,
                              void* d_out, int out_size, void* d_ws, size_t ws_size,
                              hipStream_t stream) {
    const float* zwhere = (const float*)d_in[0];
    const float* zpres  = (const float*)d_in[1];
    const float* zwhat  = (const float*)d_in[2];
    // d_in[3] z_what_scale, d_in[5] z_depth_scale: dead (only *_loc reach outputs)
    const float* zdepth = (const float*)d_in[4];
    const float* nprio  = (const float*)d_in[6];
    // d_in[7] n_objects: recover K host-side from out_size = B*K*(4+1+64+1)
    int K = out_size / (Bb * 70);

    float* out  = (float*)d_out;
    float* out0 = out;
    float* out1 = out0 + (size_t)Bb * K * 4;
    float* out2 = out1 + (size_t)Bb * K;
    float* out3 = out2 + (size_t)Bb * K * DW;

    size_t need = (size_t)Bb * K * sizeof(int);
    if (ws_size >= need) {
        int* srcws = (int*)d_ws;
        sel_kernel<false><<<Bb, TPB, 0, stream>>>(zwhere, zpres, zwhat, zdepth, nprio,
                                                  out0, out1, out2, out3, srcws, K);
        int spb = (K + BPR - 1) / BPR;
        copy_kernel<<<Bb * BPR, TPB, 0, stream>>>(zwhere, zwhat, zdepth, srcws,
                                                  out0, out1, out2, out3, K, spb);
    } else {
        sel_kernel<true><<<Bb, TPB, 0, stream>>>(zwhere, zpres, zwhat, zdepth, nprio,
                                                 out0, out1, out2, out3, nullptr, K);
    }
}

// Round 4
// 252.338 us; speedup vs baseline: 1.0390x; 1.0036x over previous
//
#include <hip/hip_runtime.h>
#include <stdint.h>

typedef unsigned int   u32;
typedef unsigned long long u64;

#define Bb   128
#define Nn   4096
#define DW   64
#define TPB  256
#define PERT 16          // contiguous slots per thread (Nn / TPB)
#define NBINS 4096
#define LCAP 512
#define CCAP 1024
#define BPR  8           // blocks per row; each does selection redundantly

// inclusive scan across the 64-lane wave
__device__ __forceinline__ int wave_iscan(int v) {
    int lane = threadIdx.x & 63;
    #pragma unroll
    for (int d = 1; d < 64; d <<= 1) {
        int u = __shfl_up(v, d, 64);
        v += (lane >= d) ? u : 0;
    }
    return v;
}

// block-wide exclusive scan over TPB threads (4 waves); 1 barrier.
// wsum must be a distinct int[4] per call site (no reuse hazard).
__device__ __forceinline__ int block_escan(int v, int* wsum) {
    int tid  = threadIdx.x;
    int wid  = tid >> 6;
    int incl = wave_iscan(v);
    if ((tid & 63) == 63) wsum[wid] = incl;
    __syncthreads();
    int base = 0;
    #pragma unroll
    for (int w = 0; w < TPB / 64; w++) base += (w < wid) ? wsum[w] : 0;
    return base + incl - v;
}

// BPR blocks per row. Each block redundantly computes the row's selection
// (deterministic -> identical compact[]), then gathers its own K-chunk.
// Single launch: no inter-kernel dependency, no workspace.
__global__ __launch_bounds__(TPB) void fused_kernel(
    const float* __restrict__ zwhere, const float* __restrict__ zpres,
    const float* __restrict__ zwhat,  const float* __restrict__ zdepth,
    const float* __restrict__ nprio,
    float* __restrict__ out0, float* __restrict__ out1,
    float* __restrict__ out2, float* __restrict__ out3,
    int K, int spb)
{
    __shared__ u32 hist[NBINS];     // 16 KB
    __shared__ u64 blist[LCAP];     //  4 KB
    __shared__ int compact[CCAP];   //  4 KB
    __shared__ int wsumA[4], wsumB[4];
    __shared__ int s_m, s_bstar, s_cbefore, s_np;
    __shared__ u64 s_thr;

    const int b     = blockIdx.x / BPR;
    const int chunk = blockIdx.x % BPR;
    const int tid   = threadIdx.x;

    for (int i = tid; i < NBINS; i += TPB) hist[i] = 0;
    if (tid == 0) { s_m = 0; s_bstar = -1; s_cbefore = 0; s_np = 0; s_thr = 0; }

    // ---- register-resident load of 16 contiguous slots (4 x float4 each) ----
    float p[PERT];
    u32 pm = 0;   // present mask, bit j = slot tid*16+j present
    {
        const float4* zp4 = (const float4*)(zpres + (size_t)b * Nn);
        const float4* pr4 = (const float4*)(nprio + (size_t)b * Nn);
        #pragma unroll
        for (int q = 0; q < 4; q++) {
            float4 z  = zp4[tid * 4 + q];
            float4 pp = pr4[tid * 4 + q];
            p[4*q+0] = pp.x; p[4*q+1] = pp.y; p[4*q+2] = pp.z; p[4*q+3] = pp.w;
            if (z.x != 0.0f) pm |= 1u << (4*q+0);
            if (z.y != 0.0f) pm |= 1u << (4*q+1);
            if (z.z != 0.0f) pm |= 1u << (4*q+2);
            if (z.w != 0.0f) pm |= 1u << (4*q+3);
        }
    }
    __syncthreads();   // hist + s_* init complete

    // ---- histogram of absent-slot priorities (value bins, monotone) ----
    #pragma unroll
    for (int j = 0; j < PERT; j++) {
        if (!((pm >> j) & 1u)) {
            int bin = (int)(p[j] * (float)NBINS);
            bin = bin < 0 ? 0 : (bin > NBINS - 1 ? NBINS - 1 : bin);
            atomicAdd(&hist[bin], 1u);
        }
    }
    // present count: wave reduce + one atomic per wave
    {
        int myp = __popc(pm);
        #pragma unroll
        for (int d = 32; d >= 1; d >>= 1) myp += __shfl_down(myp, d, 64);
        if ((tid & 63) == 0) atomicAdd(&s_np, myp);
    }
    __syncthreads();

    const int n_neg = K - s_np;

    // ---- locate boundary bin: thread t owns bins [t*16, t*16+16) ----
    int hl = 0;
    #pragma unroll
    for (int j = 0; j < 16; j++) hl += (int)hist[tid * 16 + j];
    int hbase = block_escan(hl, wsumA);
    if (n_neg > hbase && n_neg <= hbase + hl) {
        int c = hbase;
        for (int j = 0; j < 16; j++) {
            int h = (int)hist[tid * 16 + j];
            if (n_neg <= c + h) { s_bstar = tid * 16 + j; s_cbefore = c; break; }
            c += h;
        }
    }
    __syncthreads();
    const int bstar = s_bstar;
    const int r     = n_neg - s_cbefore;   // 1..hist[bstar]

    // ---- boundary-bin candidates; exact r-th smallest by (prio_bits, idx) ----
    #pragma unroll
    for (int j = 0; j < PERT; j++) {
        if (!((pm >> j) & 1u)) {
            int bin = (int)(p[j] * (float)NBINS);
            bin = bin < 0 ? 0 : (bin > NBINS - 1 ? NBINS - 1 : bin);
            if (bin == bstar) {
                int pos = atomicAdd(&s_m, 1);
                if (pos < LCAP)
                    blist[pos] = (((u64)__float_as_uint(p[j])) << 12) | (u64)(tid * PERT + j);
            }
        }
    }
    __syncthreads();
    {
        int m = s_m; if (m > LCAP) m = LCAP;
        for (int j2 = tid; j2 < m; j2 += TPB) {
            u64 kj = blist[j2];
            int rank = 0;
            for (int l = 0; l < m; l++) rank += (blist[l] < kj) ? 1 : 0;
            if (rank == r - 1) s_thr = kj;   // keys unique (index in low bits)
        }
    }
    __syncthreads();
    const u64 thr = s_thr;

    // ---- selection bits + stable compaction (index order == (tid, j) order) ----
    u32 selbits = 0, negbits = 0;
    int lc = 0;
    #pragma unroll
    for (int j = 0; j < PERT; j++) {
        bool present = (pm >> j) & 1u;
        bool neg = false;
        if (!present) {
            int bin = (int)(p[j] * (float)NBINS);
            bin = bin < 0 ? 0 : (bin > NBINS - 1 ? NBINS - 1 : bin);
            u64 key = (((u64)__float_as_uint(p[j])) << 12) | (u64)(tid * PERT + j);
            neg = (bin < bstar) || (bin == bstar && key <= thr);
        }
        if (present || neg) { selbits |= 1u << j; lc++; }
        if (neg) negbits |= 1u << j;
    }
    int pos = block_escan(lc, wsumB);
    #pragma unroll
    for (int j = 0; j < PERT; j++) {
        if ((selbits >> j) & 1u) {
            if (pos < CCAP)
                compact[pos] = (tid * PERT + j) | ((((negbits >> j) & 1u)) << 30);
            pos++;
        }
    }
    __syncthreads();

    // ---- gather this block's chunk directly from LDS compact[] ----
    const int k0 = chunk * spb;
    int k1 = k0 + spb; if (k1 > K) k1 = K;

    // z_what_loc: 16 lanes x 16 B per slot (256 B contiguous per slot)
    for (int i = k0 * 16 + tid; i < k1 * 16; i += TPB) {
        int k = i >> 4, lane = i & 15;
        int e = compact[k];
        int src = e & (Nn - 1);
        bool neg = (e >> 30) & 1;
        float4 v = make_float4(0.f, 0.f, 0.f, 0.f);
        if (!neg) v = *(const float4*)(zwhat + ((size_t)(b * Nn + src) * DW + lane * 4));
        *(float4*)(out2 + ((size_t)(b * K + k) * DW + lane * 4)) = v;
    }
    // z_where_sq (16 B) + modified (4 B) + depth (4 B): one lane per slot
    for (int k = k0 + tid; k < k1; k += TPB) {
        int e = compact[k];
        int src = e & (Nn - 1);
        bool neg = (e >> 30) & 1;
        float4 w = *(const float4*)(zwhere + (size_t)(b * Nn + src) * 4);
        float mv = (w.z >= w.w) ? w.z : w.w;   // argmax ties -> first
        float4 o; o.x = w.x; o.y = w.y; o.z = mv; o.w = mv;
        *(float4*)(out0 + (size_t)(b * K + k) * 4) = o;
        out1[(size_t)b * K + k] = neg ? -1.0f : 1.0f;   // z_present in {0,1}
        out3[(size_t)b * K + k] = neg ? 0.0f : zdepth[(size_t)b * Nn + src];
    }
}

extern "C" void kernel_launch(void* const* d_in, const int* in_sizes, int n_in,
                              void* d_out, int out_size, void* d_ws, size_t ws_size,
                              hipStream_t stream) {
    const float* zwhere = (const float*)d_in[0];
    const float* zpres  = (const float*)d_in[1];
    const float* zwhat  = (const float*)d_in[2];
    // d_in[3] z_what_scale, d_in[5] z_depth_scale: dead (only *_loc reach outputs)
    const float* zdepth = (const float*)d_in[4];
    const float* nprio  = (const float*)d_in[6];
    // d_in[7] n_objects: recover K host-side from out_size = B*K*(4+1+64+1)
    int K = out_size / (Bb * 70);

    float* out  = (float*)d_out;
    float* out0 = out;
    float* out1 = out0 + (size_t)Bb * K * 4;
    float* out2 = out1 + (size_t)Bb * K;
    float* out3 = out2 + (size_t)Bb * K * DW;

    int spb = (K + BPR - 1) / BPR;
    fused_kernel<<<Bb * BPR, TPB, 0, stream>>>(zwhere, zpres, zwhat, zdepth, nprio,
                                               out0, out1, out2, out3, K, spb);
    (void)d_ws; (void)ws_size;
}